// Round 1
// baseline (510.870 us; speedup 1.0000x reference)
//
#include <hip/hip_runtime.h>
#include <hip/hip_bf16.h>
#include <math.h>

#define NH 8
#define DKv 64
#define DVv 64
#define MIDv 128
#define DMv 512
#define BSv 8
#define NQv 100
#define NKv 100
#define QT 25

// ---------------- Kernel A: fused Linear + ELU + GroupNorm for the 4 input projections ----------------
// grid: (100 row-tiles, 4 projections), block 256. Each block: 8 rows x 512 cols.
// Output layout: [b][h][seq][d]  (i.e. ((b*NH+h)*nseq + seq)*64 + d)
__global__ __launch_bounds__(256) void proj_kernel(
    const float* __restrict__ xq, const float* __restrict__ xk, const float* __restrict__ xv,
    const float* __restrict__ Wq1, const float* __restrict__ bq1, const float* __restrict__ gq1w, const float* __restrict__ gq1b,
    const float* __restrict__ Wq2, const float* __restrict__ bq2, const float* __restrict__ gq2w, const float* __restrict__ gq2b,
    const float* __restrict__ Wk,  const float* __restrict__ bk,  const float* __restrict__ gkw,  const float* __restrict__ gkb,
    const float* __restrict__ Wv,  const float* __restrict__ bv,  const float* __restrict__ gvw,  const float* __restrict__ gvb,
    float* __restrict__ q1o, float* __restrict__ q2o, float* __restrict__ ko, float* __restrict__ vo)
{
    __shared__ float xs[8][DMv];
    const int p = blockIdx.y;
    const float *x, *W, *bb, *gw, *gb;
    float* o;
    if (p == 0)      { x = xq; W = Wq1; bb = bq1; gw = gq1w; gb = gq1b; o = q1o; }
    else if (p == 1) { x = xq; W = Wq2; bb = bq2; gw = gq2w; gb = gq2b; o = q2o; }
    else if (p == 2) { x = xk; W = Wk;  bb = bk;  gw = gkw;  gb = gkb;  o = ko;  }
    else             { x = xv; W = Wv;  bb = bv;  gw = gvw;  gb = gvb;  o = vo;  }

    const int t = threadIdx.x;
    const int r0 = blockIdx.x * 8;

    // stage 8 rows of x (8*512 floats = 1024 float4)
    const float4* xin = (const float4*)(x + (size_t)r0 * DMv);
    float4* xs4 = (float4*)xs;
#pragma unroll
    for (int i = 0; i < 4; i++) xs4[t + 256 * i] = xin[t + 256 * i];
    __syncthreads();

    const int j0 = t * 2;
    float acc0[8], acc1[8];
#pragma unroll
    for (int r = 0; r < 8; r++) { acc0[r] = 0.f; acc1[r] = 0.f; }

    for (int i = 0; i < DMv; i += 4) {
        float4 xvv[8];
#pragma unroll
        for (int r = 0; r < 8; r++) xvv[r] = *(const float4*)&xs[r][i];
#pragma unroll
        for (int ii = 0; ii < 4; ii++) {
            float2 w = *(const float2*)&W[(size_t)(i + ii) * DMv + j0];
#pragma unroll
            for (int r = 0; r < 8; r++) {
                float xr = (ii == 0) ? xvv[r].x : (ii == 1) ? xvv[r].y : (ii == 2) ? xvv[r].z : xvv[r].w;
                acc0[r] = fmaf(xr, w.x, acc0[r]);
                acc1[r] = fmaf(xr, w.y, acc1[r]);
            }
        }
    }

    const float b0 = bb[j0], b1 = bb[j0 + 1];
    const float gw0 = gw[j0], gw1 = gw[j0 + 1];
    const float gb0 = gb[j0], gb1 = gb[j0 + 1];
    const int h = j0 >> 6, d0 = j0 & 63;

#pragma unroll
    for (int r = 0; r < 8; r++) {
        float y0 = acc0[r] + b0, y1 = acc1[r] + b1;
        y0 = (y0 > 0.f) ? y0 : expm1f(y0);
        y1 = (y1 > 0.f) ? y1 : expm1f(y1);
        // group = 64 consecutive cols = 32 consecutive lanes (2 cols/lane); groups align to 32-lane halves
        float s = y0 + y1, ss = y0 * y0 + y1 * y1;
#pragma unroll
        for (int msk = 1; msk <= 16; msk <<= 1) {
            s  += __shfl_xor(s, msk);
            ss += __shfl_xor(ss, msk);
        }
        const float mu = s * (1.f / 64.f);
        const float var = ss * (1.f / 64.f) - mu * mu;
        const float rs = 1.0f / sqrtf(var + 1e-5f);
        const float o0 = (y0 - mu) * rs * gw0 + gb0;
        const float o1 = (y1 - mu) * rs * gw1 + gb1;
        const int row = r0 + r;
        const int bidx = row / NQv, sq = row % NQv;
        const size_t oi = (((size_t)(bidx * NH + h) * NQv) + sq) * 64 + d0;
        o[oi] = o0;
        o[oi + 1] = o1;
    }
}

// ---------------- Kernel B: fused low-rank attention core ----------------
// grid: (4 q-tiles, 64 bh), block 512 threads.
// per block: stage K,V (100x64 each), W_m (64x128); loop q in tile:
//   S[m,k] = relu(b_m[m] + sum_d W_m[d,m]*q1[d]*K[k,d])  (staged in LDS 128x101)
//   logits[k] = sum_m W_s[m]*S + b_s -> softmax_k ; pool[m] = mean_k S
//   ch[d] = sigmoid(b_c + sum_m pool[m]*W_c[m,d]) ; sv[d] = sum_k p[k]*V[k,d]
//   attn_v[b][q][h][d] = sv*q2[d]*ch[d]
#define B_LDS_FLOATS (6400 + 6400 + 8192 + 12928 + 128 + 128 + 416 + 512 + 128 + 128 + 64 + 64 + 512 + 512 + 64)

__global__ __launch_bounds__(512) void attn_kernel(
    const float* __restrict__ q1g, const float* __restrict__ q2g,
    const float* __restrict__ kg, const float* __restrict__ vg,
    const float* __restrict__ Wm, const float* __restrict__ bm,
    const float* __restrict__ Ws, const float* __restrict__ bs_,
    const float* __restrict__ Wc, const float* __restrict__ bc,
    float* __restrict__ attn_v)
{
    extern __shared__ float lds[];
    float* K_s    = lds;                 // 100*64
    float* V_s    = K_s + NKv * 64;      // 100*64
    float* Wm_s   = V_s + NKv * 64;      // 64*128
    float* S_s    = Wm_s + 64 * 128;     // 128*101 (pad 101: 2-way only)
    float* lg     = S_s + 128 * 101;     // 128 (logits -> softmax probs)
    float* pool_s = lg + 128;            // 128
    float* part_l = pool_s + 128;        // 4*104
    float* part_p = part_l + 4 * 104;    // 4*128
    float* ws_s   = part_p + 4 * 128;    // 128
    float* bm_s   = ws_s + 128;          // 128
    float* q1_s   = bm_s + 128;          // 64
    float* q2_s   = q1_s + 64;           // 64
    float* part_sv= q2_s + 64;           // 8*64
    float* part_ch= part_sv + 8 * 64;    // 8*64
    float* bc_s   = part_ch + 8 * 64;    // 64

    const int t = threadIdx.x;
    const int qt = blockIdx.x;     // 0..3
    const int bh = blockIdx.y;     // 0..63

    // stage K, V
    const float4* Kg4 = (const float4*)(kg + (size_t)bh * NKv * 64);
    const float4* Vg4 = (const float4*)(vg + (size_t)bh * NKv * 64);
    float4* Ks4 = (float4*)K_s;
    float4* Vs4 = (float4*)V_s;
    for (int i = t; i < NKv * 16; i += 512) { Ks4[i] = Kg4[i]; Vs4[i] = Vg4[i]; }
    // stage W_m (2048 float4)
    for (int i = t; i < 2048; i += 512) ((float4*)Wm_s)[i] = ((const float4*)Wm)[i];
    if (t < 128) { ws_s[t] = Ws[t]; bm_s[t] = bm[t]; }
    if (t < 64) bc_s[t] = bc[t];
    const float bsv = bs_[0];
    __syncthreads();

    const int m = t & 127;        // 0..127
    const int kgp = t >> 7;       // 0..3 (25 k each)

    for (int qi = 0; qi < QT; qi++) {
        const int q = qt * QT + qi;
        if (t < 64)       q1_s[t] = q1g[((size_t)bh * NQv + q) * 64 + t];
        else if (t < 128) q2_s[t - 64] = q2g[((size_t)bh * NQv + q) * 64 + (t - 64)];
        __syncthreads();

        // U[m,d] = W_m[d,m]*q1[d]
        float Wq[64];
#pragma unroll
        for (int d = 0; d < 64; d++) Wq[d] = Wm_s[d * 128 + m] * q1_s[d];
        const float bmm = bm_s[m];

        for (int i = 0; i < 25; i++) {
            const int k = kgp * 25 + i;
            const float* Kr = &K_s[k * 64];
            float a0 = 0.f, a1 = 0.f, a2 = 0.f, a3 = 0.f;
#pragma unroll
            for (int d = 0; d < 64; d += 4) {
                float4 kv = *(const float4*)&Kr[d];
                a0 = fmaf(Wq[d],     kv.x, a0);
                a1 = fmaf(Wq[d + 1], kv.y, a1);
                a2 = fmaf(Wq[d + 2], kv.z, a2);
                a3 = fmaf(Wq[d + 3], kv.w, a3);
            }
            const float s = bmm + ((a0 + a1) + (a2 + a3));
            S_s[m * 101 + k] = fmaxf(s, 0.f);
        }
        __syncthreads();

        // pool partial: this thread's m row over its 25-k chunk
        {
            float pp = 0.f;
            const int kb = kgp * 25;
            for (int i = 0; i < 25; i++) pp += S_s[m * 101 + kb + i];
            part_p[kgp * 128 + m] = pp;
        }
        // logits partial: t<400: k=t%100, c=t/100 handles 32 m's
        if (t < 400) {
            const int k = t % 100, c = t / 100;
            float pl = 0.f;
#pragma unroll
            for (int i = 0; i < 32; i++) {
                const int mm = c * 32 + i;
                pl = fmaf(ws_s[mm], S_s[mm * 101 + k], pl);
            }
            part_l[c * 104 + k] = pl;
        }
        __syncthreads();

        if (t < 64) {
            // wave 0: finalize logits + softmax over 100 (2 values/lane)
            const int l = t;
            float x0 = part_l[l] + part_l[104 + l] + part_l[208 + l] + part_l[312 + l] + bsv;
            float x1 = (l < 36) ? (part_l[l + 64] + part_l[104 + l + 64] + part_l[208 + l + 64] + part_l[312 + l + 64] + bsv)
                                : -3.0e38f;
            float mx = fmaxf(x0, x1);
#pragma unroll
            for (int msk = 1; msk <= 32; msk <<= 1) mx = fmaxf(mx, __shfl_xor(mx, msk));
            const float e0 = __expf(x0 - mx);
            const float e1 = (l < 36) ? __expf(x1 - mx) : 0.f;
            float sm = e0 + e1;
#pragma unroll
            for (int msk = 1; msk <= 32; msk <<= 1) sm += __shfl_xor(sm, msk);
            const float inv = 1.f / sm;
            lg[l] = e0 * inv;
            if (l < 36) lg[l + 64] = e1 * inv;
        } else if (t >= 128 && t < 256) {
            const int mm = t - 128;
            pool_s[mm] = (part_p[mm] + part_p[128 + mm] + part_p[256 + mm] + part_p[384 + mm]) * (1.f / (float)NKv);
        }
        __syncthreads();

        // sv & channel partials: (d = t&63, c = t>>6)
        {
            const int d = t & 63, c = t >> 6;
            float sv = 0.f;
            const int k0 = c * 13;
            const int k1 = (k0 + 13 < 100) ? (k0 + 13) : 100;
            for (int k = k0; k < k1; k++) sv = fmaf(lg[k], V_s[k * 64 + d], sv);
            part_sv[c * 64 + d] = sv;
            float ch = 0.f;
#pragma unroll
            for (int i = 0; i < 16; i++) {
                const int mm = c * 16 + i;
                ch = fmaf(pool_s[mm], Wc[mm * 64 + d], ch);
            }
            part_ch[c * 64 + d] = ch;
        }
        __syncthreads();

        if (t < 64) {
            const int d = t;
            float sv = 0.f, ch = 0.f;
#pragma unroll
            for (int c = 0; c < 8; c++) { sv += part_sv[c * 64 + d]; ch += part_ch[c * 64 + d]; }
            ch = 1.f / (1.f + __expf(-(ch + bc_s[d])));
            const float ov = sv * q2_s[d] * ch;
            const int b = bh >> 3, hh = bh & 7;
            attn_v[(((size_t)(b * NQv + q) * NH) + hh) * 64 + d] = ov;
        }
        __syncthreads();
    }
}

// ---------------- Kernel C: output projection (800x512)@(512x512)+b ----------------
__global__ __launch_bounds__(256) void out_proj_kernel(
    const float* __restrict__ x, const float* __restrict__ W, const float* __restrict__ bb,
    float* __restrict__ out)
{
    __shared__ float xs[8][DMv];
    const int t = threadIdx.x;
    const int r0 = blockIdx.x * 8;
    const float4* xin = (const float4*)(x + (size_t)r0 * DMv);
    float4* xs4 = (float4*)xs;
#pragma unroll
    for (int i = 0; i < 4; i++) xs4[t + 256 * i] = xin[t + 256 * i];
    __syncthreads();

    const int j0 = t * 2;
    float acc0[8], acc1[8];
#pragma unroll
    for (int r = 0; r < 8; r++) { acc0[r] = 0.f; acc1[r] = 0.f; }

    for (int i = 0; i < DMv; i += 4) {
        float4 xvv[8];
#pragma unroll
        for (int r = 0; r < 8; r++) xvv[r] = *(const float4*)&xs[r][i];
#pragma unroll
        for (int ii = 0; ii < 4; ii++) {
            float2 w = *(const float2*)&W[(size_t)(i + ii) * DMv + j0];
#pragma unroll
            for (int r = 0; r < 8; r++) {
                float xr = (ii == 0) ? xvv[r].x : (ii == 1) ? xvv[r].y : (ii == 2) ? xvv[r].z : xvv[r].w;
                acc0[r] = fmaf(xr, w.x, acc0[r]);
                acc1[r] = fmaf(xr, w.y, acc1[r]);
            }
        }
    }
    const float b0 = bb[j0], b1 = bb[j0 + 1];
#pragma unroll
    for (int r = 0; r < 8; r++) {
        const size_t oi = (size_t)(r0 + r) * DMv + j0;
        out[oi] = acc0[r] + b0;
        out[oi + 1] = acc1[r] + b1;
    }
}

extern "C" void kernel_launch(void* const* d_in, const int* in_sizes, int n_in,
                              void* d_out, int out_size, void* d_ws, size_t ws_size,
                              hipStream_t stream) {
    (void)in_sizes; (void)n_in; (void)out_size; (void)ws_size;
    const float* queries = (const float*)d_in[0];
    const float* keys    = (const float*)d_in[1];
    const float* values  = (const float*)d_in[2];
    const float* W_q1 = (const float*)d_in[3];
    const float* b_q1 = (const float*)d_in[4];
    const float* g_q1w = (const float*)d_in[5];
    const float* g_q1b = (const float*)d_in[6];
    const float* W_q2 = (const float*)d_in[7];
    const float* b_q2 = (const float*)d_in[8];
    const float* g_q2w = (const float*)d_in[9];
    const float* g_q2b = (const float*)d_in[10];
    const float* W_k = (const float*)d_in[11];
    const float* b_k = (const float*)d_in[12];
    const float* g_kw = (const float*)d_in[13];
    const float* g_kb = (const float*)d_in[14];
    const float* W_v = (const float*)d_in[15];
    const float* b_v = (const float*)d_in[16];
    const float* g_vw = (const float*)d_in[17];
    const float* g_vb = (const float*)d_in[18];
    const float* W_m = (const float*)d_in[19];
    const float* b_m = (const float*)d_in[20];
    const float* W_s = (const float*)d_in[21];
    const float* b_s = (const float*)d_in[22];
    const float* W_c = (const float*)d_in[23];
    const float* b_c = (const float*)d_in[24];
    const float* W_o = (const float*)d_in[25];
    const float* b_o = (const float*)d_in[26];

    float* ws = (float*)d_ws;
    const size_t PROJ = (size_t)BSv * NQv * DMv;  // 409600 floats
    float* q1 = ws;
    float* q2 = q1 + PROJ;
    float* kk = q2 + PROJ;
    float* vv = kk + PROJ;
    float* av = vv + PROJ;   // attn_v [b][q][h][d]

    proj_kernel<<<dim3(NQv * BSv / 8, 4), 256, 0, stream>>>(
        queries, keys, values,
        W_q1, b_q1, g_q1w, g_q1b,
        W_q2, b_q2, g_q2w, g_q2b,
        W_k, b_k, g_kw, g_kb,
        W_v, b_v, g_vw, g_vb,
        q1, q2, kk, vv);

    const size_t smem_b = (size_t)B_LDS_FLOATS * sizeof(float);
    hipFuncSetAttribute((const void*)attn_kernel,
                        hipFuncAttributeMaxDynamicSharedMemorySize, (int)smem_b);
    attn_kernel<<<dim3(NQv / QT, BSv * NH), 512, smem_b, stream>>>(
        q1, q2, kk, vv, W_m, b_m, W_s, b_s, W_c, b_c, av);

    out_proj_kernel<<<dim3(BSv * NQv / 8), 256, 0, stream>>>(av, W_o, b_o, (float*)d_out);
}

// Round 2
// 182.084 us; speedup vs baseline: 2.8057x; 2.8057x over previous
//
#include <hip/hip_runtime.h>
#include <hip/hip_bf16.h>
#include <math.h>

#define NH 8
#define DMv 512
#define BSv 8
#define NQv 100
#define NKv 100
#define QT 25

typedef __attribute__((ext_vector_type(8))) short short8;
typedef __attribute__((ext_vector_type(4))) float f32x4;

__device__ __forceinline__ unsigned short bf16u(float f) {
    __hip_bfloat16 h = __float2bfloat16(f);
    return *(unsigned short*)&h;
}
__device__ __forceinline__ float ubf16f(unsigned short u) {
    __hip_bfloat16 h = *(__hip_bfloat16*)&u;
    return __bfloat162float(h);
}
__device__ __forceinline__ unsigned int pkbf(float lo, float hi) {
    return ((unsigned int)bf16u(hi) << 16) | (unsigned int)bf16u(lo);
}

// ---------------- Kernel A: fused Linear + ELU + GroupNorm (4 input projections) ----------------
__global__ __launch_bounds__(256) void proj_kernel(
    const float* __restrict__ xq, const float* __restrict__ xk, const float* __restrict__ xv,
    const float* __restrict__ Wq1, const float* __restrict__ bq1, const float* __restrict__ gq1w, const float* __restrict__ gq1b,
    const float* __restrict__ Wq2, const float* __restrict__ bq2, const float* __restrict__ gq2w, const float* __restrict__ gq2b,
    const float* __restrict__ Wk,  const float* __restrict__ bk,  const float* __restrict__ gkw,  const float* __restrict__ gkb,
    const float* __restrict__ Wv,  const float* __restrict__ bv,  const float* __restrict__ gvw,  const float* __restrict__ gvb,
    float* __restrict__ q1o, float* __restrict__ q2o, float* __restrict__ ko, float* __restrict__ vo)
{
    __shared__ float xs[8][DMv];
    const int p = blockIdx.y;
    const float *x, *W, *bb, *gw, *gb;
    float* o;
    if (p == 0)      { x = xq; W = Wq1; bb = bq1; gw = gq1w; gb = gq1b; o = q1o; }
    else if (p == 1) { x = xq; W = Wq2; bb = bq2; gw = gq2w; gb = gq2b; o = q2o; }
    else if (p == 2) { x = xk; W = Wk;  bb = bk;  gw = gkw;  gb = gkb;  o = ko;  }
    else             { x = xv; W = Wv;  bb = bv;  gw = gvw;  gb = gvb;  o = vo;  }

    const int t = threadIdx.x;
    const int r0 = blockIdx.x * 8;

    const float4* xin = (const float4*)(x + (size_t)r0 * DMv);
    float4* xs4 = (float4*)xs;
#pragma unroll
    for (int i = 0; i < 4; i++) xs4[t + 256 * i] = xin[t + 256 * i];
    __syncthreads();

    const int j0 = t * 2;
    float acc0[8], acc1[8];
#pragma unroll
    for (int r = 0; r < 8; r++) { acc0[r] = 0.f; acc1[r] = 0.f; }

    for (int i = 0; i < DMv; i += 4) {
        float4 xvv[8];
#pragma unroll
        for (int r = 0; r < 8; r++) xvv[r] = *(const float4*)&xs[r][i];
#pragma unroll
        for (int ii = 0; ii < 4; ii++) {
            float2 w = *(const float2*)&W[(size_t)(i + ii) * DMv + j0];
#pragma unroll
            for (int r = 0; r < 8; r++) {
                float xr = (ii == 0) ? xvv[r].x : (ii == 1) ? xvv[r].y : (ii == 2) ? xvv[r].z : xvv[r].w;
                acc0[r] = fmaf(xr, w.x, acc0[r]);
                acc1[r] = fmaf(xr, w.y, acc1[r]);
            }
        }
    }

    const float b0 = bb[j0], b1 = bb[j0 + 1];
    const float gw0 = gw[j0], gw1 = gw[j0 + 1];
    const float gb0 = gb[j0], gb1 = gb[j0 + 1];
    const int h = j0 >> 6, d0 = j0 & 63;

#pragma unroll
    for (int r = 0; r < 8; r++) {
        float y0 = acc0[r] + b0, y1 = acc1[r] + b1;
        y0 = (y0 > 0.f) ? y0 : expm1f(y0);
        y1 = (y1 > 0.f) ? y1 : expm1f(y1);
        float s = y0 + y1, ss = y0 * y0 + y1 * y1;
#pragma unroll
        for (int msk = 1; msk <= 16; msk <<= 1) {
            s  += __shfl_xor(s, msk);
            ss += __shfl_xor(ss, msk);
        }
        const float mu = s * (1.f / 64.f);
        const float var = ss * (1.f / 64.f) - mu * mu;
        const float rs = 1.0f / sqrtf(var + 1e-5f);
        const float o0 = (y0 - mu) * rs * gw0 + gb0;
        const float o1 = (y1 - mu) * rs * gw1 + gb1;
        const int row = r0 + r;
        const int bidx = row / NQv, sq = row % NQv;
        const size_t oi = (((size_t)(bidx * NH + h) * NQv) + sq) * 64 + d0;
        o[oi] = o0;
        o[oi + 1] = o1;
    }
}

// ---------------- Kernel B v2: MFMA low-rank attention core, S never materialized ----------------
// grid (4 qtiles, 64 bh), block 512 (8 waves, split 2 Mrow x 4 Ncol).
// S[m,k] = relu(bm[m] + sum_d Wm[d,m] * (q1[d]*K[k,d])) via mfma_f32_16x16x32_bf16.
// logits[k] and pool[m] reduced straight from MFMA accumulators (S tile never stored).
#define B_LDS_BYTES 78336

__global__ __launch_bounds__(512, 2) void attn_kernel(
    const float* __restrict__ q1g, const float* __restrict__ q2g,
    const float* __restrict__ kg, const float* __restrict__ vg,
    const float* __restrict__ Wm, const float* __restrict__ bm,
    const float* __restrict__ Ws, const float* __restrict__ bs_,
    const float* __restrict__ Wc, const float* __restrict__ bc,
    float* __restrict__ attn_v)
{
    extern __shared__ char smem[];
    unsigned short* Wm_s = (unsigned short*)smem;            // [128 m][64 d] bf16, XOR-swizzled
    unsigned short* K_s  = Wm_s + 8192;                      // [128 k][64 d] bf16, XOR-swizzled (rows >=100 zero)
    unsigned int*  V_pk  = (unsigned int*)(K_s + 8192);      // [50 k2][64 d]: lo=V[2k2][d], hi=V[2k2+1][d]
    unsigned int*  Wc_pk = V_pk + 3200;                      // [64 m2][64 d]: lo=Wc[2m2][d], hi=Wc[2m2+1][d]
    float* fbase   = (float*)(Wc_pk + 4096);
    float* q1_s    = fbase;          // 64
    float* q2_s    = fbase + 64;     // 64
    float* lgp     = fbase + 128;    // 128 (softmax probs, k<100 valid)
    float* part_l2 = fbase + 256;    // [2 mrow][128 k]
    float* part_p3 = fbase + 512;    // [16 slot][132] pool partials
    float* pool_s  = fbase + 2624;   // 128
    float* part_sv = fbase + 2752;   // [8][64]
    float* part_ch = fbase + 3264;   // [8][64]
    float* ws_s    = fbase + 3776;   // 128
    float* bm_s    = fbase + 3904;   // 128
    float* bc_s    = fbase + 4032;   // 64

    const int t = threadIdx.x;
    const int qt = blockIdx.x;     // 0..3
    const int bh = blockIdx.y;     // 0..63

    const float* Kg = kg + (size_t)bh * NKv * 64;
    const float* Vg = vg + (size_t)bh * NKv * 64;

    // ---- prologue staging ----
    // K_s: 128 rows x 8 16B-units (rows >= 100 zeroed)
    for (int i = t; i < 1024; i += 512) {
        const int k = i >> 3, u = i & 7;
        uint4 w;
        if (k < NKv) {
            float4 a = *(const float4*)(Kg + k * 64 + u * 8);
            float4 b = *(const float4*)(Kg + k * 64 + u * 8 + 4);
            w.x = pkbf(a.x, a.y); w.y = pkbf(a.z, a.w);
            w.z = pkbf(b.x, b.y); w.w = pkbf(b.z, b.w);
        } else { w.x = 0u; w.y = 0u; w.z = 0u; w.w = 0u; }
        *(uint4*)((char*)K_s + k * 128 + ((u ^ (k & 7)) * 16)) = w;
    }
    // Wm_s: WmT[m][d] = Wm[d*128+m]
    for (int i = t; i < 1024; i += 512) {
        const int u = i >> 7, m = i & 127;
        float f[8];
#pragma unroll
        for (int j = 0; j < 8; j++) f[j] = Wm[(size_t)(u * 8 + j) * 128 + m];
        uint4 w;
        w.x = pkbf(f[0], f[1]); w.y = pkbf(f[2], f[3]);
        w.z = pkbf(f[4], f[5]); w.w = pkbf(f[6], f[7]);
        *(uint4*)((char*)Wm_s + m * 128 + ((u ^ (m & 7)) * 16)) = w;
    }
    // V_pk: 50 k2 x 16 4-d units
    for (int i = t; i < 800; i += 512) {
        const int k2 = i >> 4, du = i & 15;
        float4 a = *(const float4*)(Vg + (size_t)(2 * k2) * 64 + du * 4);
        float4 b = *(const float4*)(Vg + (size_t)(2 * k2 + 1) * 64 + du * 4);
        uint4 w;
        w.x = pkbf(a.x, b.x); w.y = pkbf(a.y, b.y);
        w.z = pkbf(a.z, b.z); w.w = pkbf(a.w, b.w);
        *(uint4*)(V_pk + k2 * 64 + du * 4) = w;
    }
    // Wc_pk: 64 m2 x 16 4-d units
    for (int i = t; i < 1024; i += 512) {
        const int m2 = i >> 4, du = i & 15;
        float4 a = *(const float4*)(Wc + (size_t)(2 * m2) * 64 + du * 4);
        float4 b = *(const float4*)(Wc + (size_t)(2 * m2 + 1) * 64 + du * 4);
        uint4 w;
        w.x = pkbf(a.x, b.x); w.y = pkbf(a.y, b.y);
        w.z = pkbf(a.z, b.z); w.w = pkbf(a.w, b.w);
        *(uint4*)(Wc_pk + m2 * 64 + du * 4) = w;
    }
    if (t < 128) { ws_s[t] = Ws[t]; bm_s[t] = bm[t]; }
    if (t < 64) bc_s[t] = bc[t];
    {   // initial q1/q2 preload for q = qt*QT
        const int tq = t - 256;
        const size_t qb = ((size_t)bh * NQv + qt * QT) * 64;
        if (tq >= 0 && tq < 64) q1_s[tq] = q1g[qb + tq];
        else if (tq >= 64 && tq < 128) q2_s[tq - 64] = q2g[qb + (tq - 64)];
    }
    const float bsv = bs_[0];
    __syncthreads();

    // ---- persistent per-wave fragments ----
    const int lane = t & 63, wave = t >> 6;
    const int mrow = wave >> 2, ncol = wave & 3;
    const int lr = lane & 15, lq = lane >> 4;

    short8 afr[4][2];
#pragma unroll
    for (int mti = 0; mti < 4; mti++)
#pragma unroll
        for (int ks = 0; ks < 2; ks++) {
            const int m = mrow * 64 + mti * 16 + lr;
            const int u = ks * 4 + lq;
            afr[mti][ks] = *(const short8*)((const char*)Wm_s + m * 128 + ((u ^ (m & 7)) * 16));
        }
    float kf[2][2][8];
#pragma unroll
    for (int nti = 0; nti < 2; nti++)
#pragma unroll
        for (int ks = 0; ks < 2; ks++) {
            const int k = ncol * 32 + nti * 16 + lr;
            const int u = ks * 4 + lq;
            union { short8 s; unsigned short us[8]; } kb;
            kb.s = *(const short8*)((const char*)K_s + k * 128 + ((u ^ (k & 7)) * 16));
#pragma unroll
            for (int j = 0; j < 8; j++) kf[nti][ks][j] = ubf16f(kb.us[j]);
        }
    float bmr[4][4], wsr[4][4];
#pragma unroll
    for (int mti = 0; mti < 4; mti++)
#pragma unroll
        for (int r = 0; r < 4; r++) {
            const int m = mrow * 64 + mti * 16 + lq * 4 + r;
            bmr[mti][r] = bm_s[m];
            wsr[mti][r] = ws_s[m];
        }
    const float km0 = (ncol * 32 + lr < 100) ? 1.f : 0.f;
    const float km1 = (ncol * 32 + 16 + lr < 100) ? 1.f : 0.f;

    // ---- q loop ----
    for (int qi = 0; qi < QT; qi++) {
        const int q = qt * QT + qi;

        // phase b: form B' = q1 (.) K in-reg, MFMA, fused logits/pool partials
        float q1f[2][8];
#pragma unroll
        for (int ks = 0; ks < 2; ks++) {
            float4 x = *(const float4*)((const char*)q1_s + ks * 128 + lq * 32);
            float4 y = *(const float4*)((const char*)q1_s + ks * 128 + lq * 32 + 16);
            q1f[ks][0] = x.x; q1f[ks][1] = x.y; q1f[ks][2] = x.z; q1f[ks][3] = x.w;
            q1f[ks][4] = y.x; q1f[ks][5] = y.y; q1f[ks][6] = y.z; q1f[ks][7] = y.w;
        }
        f32x4 acc[4][2];
#pragma unroll
        for (int mti = 0; mti < 4; mti++)
#pragma unroll
            for (int nti = 0; nti < 2; nti++) acc[mti][nti] = (f32x4){0.f, 0.f, 0.f, 0.f};

#pragma unroll
        for (int ks = 0; ks < 2; ks++) {
            union { short8 s; unsigned int u[4]; } bfr0, bfr1;
#pragma unroll
            for (int j = 0; j < 8; j += 2) {
                bfr0.u[j >> 1] = pkbf(kf[0][ks][j] * q1f[ks][j], kf[0][ks][j + 1] * q1f[ks][j + 1]);
                bfr1.u[j >> 1] = pkbf(kf[1][ks][j] * q1f[ks][j], kf[1][ks][j + 1] * q1f[ks][j + 1]);
            }
#pragma unroll
            for (int mti = 0; mti < 4; mti++) {
                acc[mti][0] = __builtin_amdgcn_mfma_f32_16x16x32_bf16(afr[mti][ks], bfr0.s, acc[mti][0], 0, 0, 0);
                acc[mti][1] = __builtin_amdgcn_mfma_f32_16x16x32_bf16(afr[mti][ks], bfr1.s, acc[mti][1], 0, 0, 0);
            }
        }

        float lp0 = 0.f, lp1 = 0.f;
        float ppv[4][4];
#pragma unroll
        for (int mti = 0; mti < 4; mti++) {
#pragma unroll
            for (int r = 0; r < 4; r++) {
                const float v0 = fmaxf(acc[mti][0][r] + bmr[mti][r], 0.f);
                const float v1 = fmaxf(acc[mti][1][r] + bmr[mti][r], 0.f);
                lp0 = fmaf(wsr[mti][r], v0, lp0);
                lp1 = fmaf(wsr[mti][r], v1, lp1);
                float pp = v0 * km0 + v1 * km1;
                pp += __shfl_xor(pp, 1);
                pp += __shfl_xor(pp, 2);
                ppv[mti][r] = pp;
            }
        }
        if ((lr & 3) == 0) {
            const int slot = ncol * 4 + (lr >> 2);
#pragma unroll
            for (int mti = 0; mti < 4; mti++) {
                const int m0 = mrow * 64 + mti * 16 + lq * 4;
                *(float4*)(part_p3 + slot * 132 + m0) =
                    make_float4(ppv[mti][0], ppv[mti][1], ppv[mti][2], ppv[mti][3]);
            }
        }
        lp0 += __shfl_xor(lp0, 16); lp0 += __shfl_xor(lp0, 32);
        lp1 += __shfl_xor(lp1, 16); lp1 += __shfl_xor(lp1, 32);
        if (lane < 16) part_l2[mrow * 128 + ncol * 32 + lane] = lp0;
        else if (lane < 32) part_l2[mrow * 128 + ncol * 32 + lane] = lp1;
        __syncthreads();

        // phase e: softmax (wave 0) + pool finalize (threads 128..255)
        if (t < 64) {
            const int l = t;
            float x0 = part_l2[l] + part_l2[128 + l] + bsv;
            float x1 = (l < 36) ? (part_l2[64 + l] + part_l2[192 + l] + bsv) : -3.0e38f;
            float mx = fmaxf(x0, x1);
#pragma unroll
            for (int msk = 1; msk <= 32; msk <<= 1) mx = fmaxf(mx, __shfl_xor(mx, msk));
            const float e0 = __expf(x0 - mx);
            const float e1 = (l < 36) ? __expf(x1 - mx) : 0.f;
            float sm = e0 + e1;
#pragma unroll
            for (int msk = 1; msk <= 32; msk <<= 1) sm += __shfl_xor(sm, msk);
            const float inv = 1.f / sm;
            lgp[l] = e0 * inv;
            if (l < 36) lgp[64 + l] = e1 * inv;
        } else if (t >= 128 && t < 256) {
            const int mm = t - 128;
            float s = 0.f;
#pragma unroll
            for (int sl = 0; sl < 16; sl++) s += part_p3[sl * 132 + mm];
            pool_s[mm] = s * 0.01f;
        }
        __syncthreads();

        // phase f: sv / ch partials (c = wave handles k2/m2 chunk)
        float q2v = 0.f;
        {
            const int d = t & 63, c = t >> 6;
            float sv = 0.f;
            const int k20 = c * 7;
            const int k21 = (k20 + 7 < 50) ? (k20 + 7) : 50;
            for (int k2 = k20; k2 < k21; k2++) {
                const unsigned int vp = V_pk[k2 * 64 + d];
                const float2 lp = *(const float2*)(lgp + 2 * k2);
                sv = fmaf(lp.x, ubf16f((unsigned short)(vp & 0xffffu)), sv);
                sv = fmaf(lp.y, ubf16f((unsigned short)(vp >> 16)), sv);
            }
            part_sv[c * 64 + d] = sv;
            float ch = 0.f;
#pragma unroll
            for (int i = 0; i < 8; i++) {
                const int m2 = c * 8 + i;
                const unsigned int wp = Wc_pk[m2 * 64 + d];
                const float2 pl = *(const float2*)(pool_s + 2 * m2);
                ch = fmaf(pl.x, ubf16f((unsigned short)(wp & 0xffffu)), ch);
                ch = fmaf(pl.y, ubf16f((unsigned short)(wp >> 16)), ch);
            }
            part_ch[c * 64 + d] = ch;
            if (t < 64) q2v = q2_s[t];
        }
        __syncthreads();

        // phase g: final output + preload next q1/q2
        if (t < 64) {
            const int d = t;
            float sv = 0.f, ch = 0.f;
#pragma unroll
            for (int c = 0; c < 8; c++) { sv += part_sv[c * 64 + d]; ch += part_ch[c * 64 + d]; }
            ch = 1.f / (1.f + __expf(-(ch + bc_s[d])));
            const float ov = sv * q2v * ch;
            const int b = bh >> 3, hh = bh & 7;
            attn_v[(((size_t)(b * NQv + q) * NH) + hh) * 64 + d] = ov;
        } else if (qi + 1 < QT) {
            const int tq = t - 256;
            const size_t qb = ((size_t)bh * NQv + (q + 1)) * 64;
            if (tq >= 0 && tq < 64) q1_s[tq] = q1g[qb + tq];
            else if (tq >= 64 && tq < 128) q2_s[tq - 64] = q2g[qb + (tq - 64)];
        }
        __syncthreads();
    }
}

// ---------------- Kernel C: output projection (800x512)@(512x512)+b ----------------
__global__ __launch_bounds__(256) void out_proj_kernel(
    const float* __restrict__ x, const float* __restrict__ W, const float* __restrict__ bb,
    float* __restrict__ out)
{
    __shared__ float xs[8][DMv];
    const int t = threadIdx.x;
    const int r0 = blockIdx.x * 8;
    const float4* xin = (const float4*)(x + (size_t)r0 * DMv);
    float4* xs4 = (float4*)xs;
#pragma unroll
    for (int i = 0; i < 4; i++) xs4[t + 256 * i] = xin[t + 256 * i];
    __syncthreads();

    const int j0 = t * 2;
    float acc0[8], acc1[8];
#pragma unroll
    for (int r = 0; r < 8; r++) { acc0[r] = 0.f; acc1[r] = 0.f; }

    for (int i = 0; i < DMv; i += 4) {
        float4 xvv[8];
#pragma unroll
        for (int r = 0; r < 8; r++) xvv[r] = *(const float4*)&xs[r][i];
#pragma unroll
        for (int ii = 0; ii < 4; ii++) {
            float2 w = *(const float2*)&W[(size_t)(i + ii) * DMv + j0];
#pragma unroll
            for (int r = 0; r < 8; r++) {
                float xr = (ii == 0) ? xvv[r].x : (ii == 1) ? xvv[r].y : (ii == 2) ? xvv[r].z : xvv[r].w;
                acc0[r] = fmaf(xr, w.x, acc0[r]);
                acc1[r] = fmaf(xr, w.y, acc1[r]);
            }
        }
    }
    const float b0 = bb[j0], b1 = bb[j0 + 1];
#pragma unroll
    for (int r = 0; r < 8; r++) {
        const size_t oi = (size_t)(r0 + r) * DMv + j0;
        out[oi] = acc0[r] + b0;
        out[oi + 1] = acc1[r] + b1;
    }
}

extern "C" void kernel_launch(void* const* d_in, const int* in_sizes, int n_in,
                              void* d_out, int out_size, void* d_ws, size_t ws_size,
                              hipStream_t stream) {
    (void)in_sizes; (void)n_in; (void)out_size; (void)ws_size;
    const float* queries = (const float*)d_in[0];
    const float* keys    = (const float*)d_in[1];
    const float* values  = (const float*)d_in[2];
    const float* W_q1 = (const float*)d_in[3];
    const float* b_q1 = (const float*)d_in[4];
    const float* g_q1w = (const float*)d_in[5];
    const float* g_q1b = (const float*)d_in[6];
    const float* W_q2 = (const float*)d_in[7];
    const float* b_q2 = (const float*)d_in[8];
    const float* g_q2w = (const float*)d_in[9];
    const float* g_q2b = (const float*)d_in[10];
    const float* W_k = (const float*)d_in[11];
    const float* b_k = (const float*)d_in[12];
    const float* g_kw = (const float*)d_in[13];
    const float* g_kb = (const float*)d_in[14];
    const float* W_v = (const float*)d_in[15];
    const float* b_v = (const float*)d_in[16];
    const float* g_vw = (const float*)d_in[17];
    const float* g_vb = (const float*)d_in[18];
    const float* W_m = (const float*)d_in[19];
    const float* b_m = (const float*)d_in[20];
    const float* W_s = (const float*)d_in[21];
    const float* b_s = (const float*)d_in[22];
    const float* W_c = (const float*)d_in[23];
    const float* b_c = (const float*)d_in[24];
    const float* W_o = (const float*)d_in[25];
    const float* b_o = (const float*)d_in[26];

    float* ws = (float*)d_ws;
    const size_t PROJ = (size_t)BSv * NQv * 64 * NH;  // 409600 floats
    float* q1 = ws;
    float* q2 = q1 + PROJ;
    float* kk = q2 + PROJ;
    float* vv = kk + PROJ;
    float* av = vv + PROJ;   // attn_v [b][q][h][d]

    proj_kernel<<<dim3(NQv * BSv / 8, 4), 256, 0, stream>>>(
        queries, keys, values,
        W_q1, b_q1, g_q1w, g_q1b,
        W_q2, b_q2, g_q2w, g_q2b,
        W_k, b_k, g_kw, g_kb,
        W_v, b_v, g_vw, g_vb,
        q1, q2, kk, vv);

    hipFuncSetAttribute((const void*)attn_kernel,
                        hipFuncAttributeMaxDynamicSharedMemorySize, B_LDS_BYTES);
    attn_kernel<<<dim3(NQv / QT, BSv * NH), 512, B_LDS_BYTES, stream>>>(
        q1, q2, kk, vv, W_m, b_m, W_s, b_s, W_c, b_c, av);

    out_proj_kernel<<<dim3(BSv * NQv / 8), 256, 0, stream>>>(av, W_o, b_o, (float*)d_out);
}

// Round 3
// 129.864 us; speedup vs baseline: 3.9339x; 1.4021x over previous
//
#include <hip/hip_runtime.h>
#include <hip/hip_bf16.h>
#include <math.h>

#define NH 8
#define DMv 512
#define BSv 8
#define NQv 100
#define NKv 100

typedef __attribute__((ext_vector_type(8))) short short8;
typedef __attribute__((ext_vector_type(4))) float f32x4;

__device__ __forceinline__ unsigned short bf16u(float f) {
    __hip_bfloat16 h = __float2bfloat16(f);
    return *(unsigned short*)&h;
}
__device__ __forceinline__ float ubf16f(unsigned short u) {
    __hip_bfloat16 h = *(__hip_bfloat16*)&u;
    return __bfloat162float(h);
}
__device__ __forceinline__ unsigned int pkbf(float lo, float hi) {
    return ((unsigned int)bf16u(hi) << 16) | (unsigned int)bf16u(lo);
}

// ---------------- Kernel 0: weight transpose + bf16 convert ----------------
// W [512 k][512 n] fp32 -> WT [512 n][512 k] bf16.  grid (8 ktiles, 8 ntiles, 5 weights)
__global__ __launch_bounds__(256) void wt_kernel(
    const float* __restrict__ W_q1, const float* __restrict__ W_q2,
    const float* __restrict__ W_k,  const float* __restrict__ W_v,
    const float* __restrict__ W_o,  unsigned short* __restrict__ wt)
{
    __shared__ float tile[64][68];
    const int z = blockIdx.z;
    const float* W = (z == 0) ? W_q1 : (z == 1) ? W_q2 : (z == 2) ? W_k : (z == 3) ? W_v : W_o;
    unsigned short* out = wt + (size_t)z * 512 * 512;
    const int k0 = blockIdx.x * 64, n0 = blockIdx.y * 64;
    const int t = threadIdx.x;
    const int r = t >> 2, c = t & 3;
#pragma unroll
    for (int i = 0; i < 4; i++) {
        float4 v = *(const float4*)&W[(size_t)(k0 + r) * 512 + n0 + c * 16 + i * 4];
        *(float4*)&tile[r][c * 16 + i * 4] = v;
    }
    __syncthreads();
#pragma unroll
    for (int jj = 0; jj < 4; jj++) {
        const int kb = c * 16 + jj * 4;
        ushort4 u;
        u.x = bf16u(tile[kb + 0][r]); u.y = bf16u(tile[kb + 1][r]);
        u.z = bf16u(tile[kb + 2][r]); u.w = bf16u(tile[kb + 3][r]);
        *(ushort4*)&out[(size_t)(n0 + r) * 512 + k0 + kb] = u;
    }
}

// ---------------- Kernel A: MFMA proj GEMM + bias + ELU + GroupNorm ----------------
// grid (13 rowtiles, 8 coltiles(=head), 4 proj), 256 thr (4 waves, 2x2 of 32x32).
// BM=64 BN=64 BK=64. B from pre-transposed bf16 WT. Epilogue: ELU -> LDS Y -> GN.
__global__ __launch_bounds__(256) void proj_kernel(
    const float* __restrict__ xq, const float* __restrict__ xk, const float* __restrict__ xv,
    const unsigned short* __restrict__ wt,
    const float* __restrict__ bq1, const float* __restrict__ gq1w, const float* __restrict__ gq1b,
    const float* __restrict__ bq2, const float* __restrict__ gq2w, const float* __restrict__ gq2b,
    const float* __restrict__ bk,  const float* __restrict__ gkw,  const float* __restrict__ gkb,
    const float* __restrict__ bv,  const float* __restrict__ gvw,  const float* __restrict__ gvb,
    float* __restrict__ q1o, float* __restrict__ q2o, float* __restrict__ ko, float* __restrict__ vo)
{
    __shared__ char A_s[64 * 144];
    __shared__ char B_s[64 * 144];
    __shared__ float Y_s[64][68];

    const int p = blockIdx.z;
    const float *x, *bb, *gw, *gb;
    float* o;
    if (p == 0)      { x = xq; bb = bq1; gw = gq1w; gb = gq1b; o = q1o; }
    else if (p == 1) { x = xq; bb = bq2; gw = gq2w; gb = gq2b; o = q2o; }
    else if (p == 2) { x = xk; bb = bk;  gw = gkw;  gb = gkb;  o = ko;  }
    else             { x = xv; bb = bv;  gw = gvw;  gb = gvb;  o = vo;  }
    const unsigned short* WT = wt + (size_t)p * 512 * 512;

    const int t = threadIdx.x;
    const int r0 = blockIdx.x * 64;
    const int ct = blockIdx.y;

    const int lane = t & 63, wave = t >> 6;
    const int wr = wave >> 1, wc = wave & 1;
    const int lr = lane & 15, lq = lane >> 4;

    const int srow = t >> 2, sc = t & 3;   // staging: row 0..63, 2 units each

    f32x4 acc[2][2];
#pragma unroll
    for (int i = 0; i < 2; i++)
#pragma unroll
        for (int j = 0; j < 2; j++) acc[i][j] = (f32x4){0.f, 0.f, 0.f, 0.f};

    const int arow = (r0 + srow < 800) ? (r0 + srow) : 799;

    for (int kk = 0; kk < 8; kk++) {
        const int k0 = kk * 64;
        // stage A (X fp32 -> bf16)
#pragma unroll
        for (int uu = 0; uu < 2; uu++) {
            const int u = sc * 2 + uu;
            float4 f0 = *(const float4*)&x[(size_t)arow * 512 + k0 + u * 8];
            float4 f1 = *(const float4*)&x[(size_t)arow * 512 + k0 + u * 8 + 4];
            uint4 w;
            w.x = pkbf(f0.x, f0.y); w.y = pkbf(f0.z, f0.w);
            w.z = pkbf(f1.x, f1.y); w.w = pkbf(f1.z, f1.w);
            *(uint4*)(A_s + srow * 144 + u * 16) = w;
        }
        // stage B (WT bf16 copy)
#pragma unroll
        for (int uu = 0; uu < 2; uu++) {
            const int u = sc * 2 + uu;
            uint4 w = *(const uint4*)((const char*)(WT + (size_t)(ct * 64 + srow) * 512 + k0) + u * 16);
            *(uint4*)(B_s + srow * 144 + u * 16) = w;
        }
        __syncthreads();
#pragma unroll
        for (int ks = 0; ks < 2; ks++) {
            short8 a0 = *(const short8*)(A_s + (wr * 32 + lr) * 144 + (ks * 4 + lq) * 16);
            short8 a1 = *(const short8*)(A_s + (wr * 32 + 16 + lr) * 144 + (ks * 4 + lq) * 16);
            short8 b0 = *(const short8*)(B_s + (wc * 32 + lr) * 144 + (ks * 4 + lq) * 16);
            short8 b1 = *(const short8*)(B_s + (wc * 32 + 16 + lr) * 144 + (ks * 4 + lq) * 16);
            acc[0][0] = __builtin_amdgcn_mfma_f32_16x16x32_bf16(a0, b0, acc[0][0], 0, 0, 0);
            acc[0][1] = __builtin_amdgcn_mfma_f32_16x16x32_bf16(a0, b1, acc[0][1], 0, 0, 0);
            acc[1][0] = __builtin_amdgcn_mfma_f32_16x16x32_bf16(a1, b0, acc[1][0], 0, 0, 0);
            acc[1][1] = __builtin_amdgcn_mfma_f32_16x16x32_bf16(a1, b1, acc[1][1], 0, 0, 0);
        }
        __syncthreads();
    }

    // epilogue: bias + ELU into Y_s
#pragma unroll
    for (int nt = 0; nt < 2; nt++) {
        const int colL = wc * 32 + nt * 16 + lr;
        const float bias = bb[ct * 64 + colL];
#pragma unroll
        for (int mt = 0; mt < 2; mt++) {
#pragma unroll
            for (int r = 0; r < 4; r++) {
                const int row = wr * 32 + mt * 16 + lq * 4 + r;
                float y = acc[mt][nt][r] + bias;
                y = (y > 0.f) ? y : expm1f(y);
                Y_s[row][colL] = y;
            }
        }
    }
    __syncthreads();

    // GroupNorm over the 64-col group (this block's col tile == one head group)
    {
        const int row = t >> 2, c = t & 3;
        float v[16];
        float s = 0.f, ss = 0.f;
#pragma unroll
        for (int i = 0; i < 16; i++) {
            v[i] = Y_s[row][c * 16 + i];
            s += v[i]; ss += v[i] * v[i];
        }
        s += __shfl_xor(s, 1); ss += __shfl_xor(ss, 1);
        s += __shfl_xor(s, 2); ss += __shfl_xor(ss, 2);
        const float mu = s * (1.f / 64.f);
        const float var = ss * (1.f / 64.f) - mu * mu;
        const float rs = 1.0f / sqrtf(var + 1e-5f);
        const int rowg = r0 + row;
        if (rowg < 800) {
            const int b = rowg / 100, sq = rowg % 100;
            const size_t base = (((size_t)(b * NH + ct) * NQv) + sq) * 64 + c * 16;
            const int j0 = ct * 64 + c * 16;
#pragma unroll
            for (int i4 = 0; i4 < 4; i4++) {
                float4 gwv = *(const float4*)&gw[j0 + i4 * 4];
                float4 gbv = *(const float4*)&gb[j0 + i4 * 4];
                float4 ov;
                ov.x = (v[i4 * 4 + 0] - mu) * rs * gwv.x + gbv.x;
                ov.y = (v[i4 * 4 + 1] - mu) * rs * gwv.y + gbv.y;
                ov.z = (v[i4 * 4 + 2] - mu) * rs * gwv.z + gbv.z;
                ov.w = (v[i4 * 4 + 3] - mu) * rs * gwv.w + gbv.w;
                *(float4*)&o[base + i4 * 4] = ov;
            }
        }
    }
}

// ---------------- Kernel B: MFMA low-rank attention core (S never materialized) ----------------
#define B_LDS_BYTES 78336

__global__ __launch_bounds__(512, 2) void attn_kernel(
    const float* __restrict__ q1g, const float* __restrict__ q2g,
    const float* __restrict__ kg, const float* __restrict__ vg,
    const float* __restrict__ Wm, const float* __restrict__ bm,
    const float* __restrict__ Ws, const float* __restrict__ bs_,
    const float* __restrict__ Wc, const float* __restrict__ bc,
    float* __restrict__ attn_v)
{
    extern __shared__ char smem[];
    unsigned short* Wm_s = (unsigned short*)smem;            // [128 m][64 d] bf16, XOR-swizzled
    unsigned short* K_s  = Wm_s + 8192;                      // [128 k][64 d] bf16, XOR-swizzled
    unsigned int*  V_pk  = (unsigned int*)(K_s + 8192);      // [50 k2][64 d] packed pair
    unsigned int*  Wc_pk = V_pk + 3200;                      // [64 m2][64 d] packed pair
    float* fbase   = (float*)(Wc_pk + 4096);
    float* q1_s    = fbase;
    float* q2_s    = fbase + 64;
    float* lgp     = fbase + 128;
    float* part_l2 = fbase + 256;    // [2][128]
    float* part_p3 = fbase + 512;    // [16][132]
    float* pool_s  = fbase + 2624;
    float* part_sv = fbase + 2752;   // [8][64]
    float* part_ch = fbase + 3264;   // [8][64]
    float* ws_s    = fbase + 3776;
    float* bm_s    = fbase + 3904;
    float* bc_s    = fbase + 4032;

    const int t = threadIdx.x;
    const int qt = blockIdx.x;     // 0..7
    const int bh = blockIdx.y;     // 0..63
    const int q0 = (qt < 4) ? qt * 13 : 52 + (qt - 4) * 12;
    const int nq = (qt < 4) ? 13 : 12;

    const float* Kg = kg + (size_t)bh * NKv * 64;
    const float* Vg = vg + (size_t)bh * NKv * 64;

    for (int i = t; i < 1024; i += 512) {
        const int k = i >> 3, u = i & 7;
        uint4 w;
        if (k < NKv) {
            float4 a = *(const float4*)(Kg + k * 64 + u * 8);
            float4 b = *(const float4*)(Kg + k * 64 + u * 8 + 4);
            w.x = pkbf(a.x, a.y); w.y = pkbf(a.z, a.w);
            w.z = pkbf(b.x, b.y); w.w = pkbf(b.z, b.w);
        } else { w.x = 0u; w.y = 0u; w.z = 0u; w.w = 0u; }
        *(uint4*)((char*)K_s + k * 128 + ((u ^ (k & 7)) * 16)) = w;
    }
    for (int i = t; i < 1024; i += 512) {
        const int u = i >> 7, m = i & 127;
        float f[8];
#pragma unroll
        for (int j = 0; j < 8; j++) f[j] = Wm[(size_t)(u * 8 + j) * 128 + m];
        uint4 w;
        w.x = pkbf(f[0], f[1]); w.y = pkbf(f[2], f[3]);
        w.z = pkbf(f[4], f[5]); w.w = pkbf(f[6], f[7]);
        *(uint4*)((char*)Wm_s + m * 128 + ((u ^ (m & 7)) * 16)) = w;
    }
    for (int i = t; i < 800; i += 512) {
        const int k2 = i >> 4, du = i & 15;
        float4 a = *(const float4*)(Vg + (size_t)(2 * k2) * 64 + du * 4);
        float4 b = *(const float4*)(Vg + (size_t)(2 * k2 + 1) * 64 + du * 4);
        uint4 w;
        w.x = pkbf(a.x, b.x); w.y = pkbf(a.y, b.y);
        w.z = pkbf(a.z, b.z); w.w = pkbf(a.w, b.w);
        *(uint4*)(V_pk + k2 * 64 + du * 4) = w;
    }
    for (int i = t; i < 1024; i += 512) {
        const int m2 = i >> 4, du = i & 15;
        float4 a = *(const float4*)(Wc + (size_t)(2 * m2) * 64 + du * 4);
        float4 b = *(const float4*)(Wc + (size_t)(2 * m2 + 1) * 64 + du * 4);
        uint4 w;
        w.x = pkbf(a.x, b.x); w.y = pkbf(a.y, b.y);
        w.z = pkbf(a.z, b.z); w.w = pkbf(a.w, b.w);
        *(uint4*)(Wc_pk + m2 * 64 + du * 4) = w;
    }
    if (t < 128) { ws_s[t] = Ws[t]; bm_s[t] = bm[t]; }
    if (t < 64) bc_s[t] = bc[t];
    {
        const int tq = t - 256;
        const size_t qb = ((size_t)bh * NQv + q0) * 64;
        if (tq >= 0 && tq < 64) q1_s[tq] = q1g[qb + tq];
        else if (tq >= 64 && tq < 128) q2_s[tq - 64] = q2g[qb + (tq - 64)];
    }
    const float bsv = bs_[0];
    __syncthreads();

    const int lane = t & 63, wave = t >> 6;
    const int mrow = wave >> 2, ncol = wave & 3;
    const int lr = lane & 15, lq = lane >> 4;

    short8 afr[4][2];
#pragma unroll
    for (int mti = 0; mti < 4; mti++)
#pragma unroll
        for (int ks = 0; ks < 2; ks++) {
            const int m = mrow * 64 + mti * 16 + lr;
            const int u = ks * 4 + lq;
            afr[mti][ks] = *(const short8*)((const char*)Wm_s + m * 128 + ((u ^ (m & 7)) * 16));
        }
    float kf[2][2][8];
#pragma unroll
    for (int nti = 0; nti < 2; nti++)
#pragma unroll
        for (int ks = 0; ks < 2; ks++) {
            const int k = ncol * 32 + nti * 16 + lr;
            const int u = ks * 4 + lq;
            union { short8 s; unsigned short us[8]; } kb;
            kb.s = *(const short8*)((const char*)K_s + k * 128 + ((u ^ (k & 7)) * 16));
#pragma unroll
            for (int j = 0; j < 8; j++) kf[nti][ks][j] = ubf16f(kb.us[j]);
        }
    float bmr[4][4], wsr[4][4];
#pragma unroll
    for (int mti = 0; mti < 4; mti++)
#pragma unroll
        for (int r = 0; r < 4; r++) {
            const int m = mrow * 64 + mti * 16 + lq * 4 + r;
            bmr[mti][r] = bm_s[m];
            wsr[mti][r] = ws_s[m];
        }
    const float km0 = (ncol * 32 + lr < 100) ? 1.f : 0.f;
    const float km1 = (ncol * 32 + 16 + lr < 100) ? 1.f : 0.f;

    for (int qi = 0; qi < nq; qi++) {
        const int q = q0 + qi;

        float q1f[2][8];
#pragma unroll
        for (int ks = 0; ks < 2; ks++) {
            float4 x = *(const float4*)((const char*)q1_s + ks * 128 + lq * 32);
            float4 y = *(const float4*)((const char*)q1_s + ks * 128 + lq * 32 + 16);
            q1f[ks][0] = x.x; q1f[ks][1] = x.y; q1f[ks][2] = x.z; q1f[ks][3] = x.w;
            q1f[ks][4] = y.x; q1f[ks][5] = y.y; q1f[ks][6] = y.z; q1f[ks][7] = y.w;
        }
        f32x4 acc[4][2];
#pragma unroll
        for (int mti = 0; mti < 4; mti++)
#pragma unroll
            for (int nti = 0; nti < 2; nti++) acc[mti][nti] = (f32x4){0.f, 0.f, 0.f, 0.f};

#pragma unroll
        for (int ks = 0; ks < 2; ks++) {
            union { short8 s; unsigned int u[4]; } bfr0, bfr1;
#pragma unroll
            for (int j = 0; j < 8; j += 2) {
                bfr0.u[j >> 1] = pkbf(kf[0][ks][j] * q1f[ks][j], kf[0][ks][j + 1] * q1f[ks][j + 1]);
                bfr1.u[j >> 1] = pkbf(kf[1][ks][j] * q1f[ks][j], kf[1][ks][j + 1] * q1f[ks][j + 1]);
            }
#pragma unroll
            for (int mti = 0; mti < 4; mti++) {
                acc[mti][0] = __builtin_amdgcn_mfma_f32_16x16x32_bf16(afr[mti][ks], bfr0.s, acc[mti][0], 0, 0, 0);
                acc[mti][1] = __builtin_amdgcn_mfma_f32_16x16x32_bf16(afr[mti][ks], bfr1.s, acc[mti][1], 0, 0, 0);
            }
        }

        float lp0 = 0.f, lp1 = 0.f;
        float ppv[4][4];
#pragma unroll
        for (int mti = 0; mti < 4; mti++) {
#pragma unroll
            for (int r = 0; r < 4; r++) {
                const float v0 = fmaxf(acc[mti][0][r] + bmr[mti][r], 0.f);
                const float v1 = fmaxf(acc[mti][1][r] + bmr[mti][r], 0.f);
                lp0 = fmaf(wsr[mti][r], v0, lp0);
                lp1 = fmaf(wsr[mti][r], v1, lp1);
                float pp = v0 * km0 + v1 * km1;
                pp += __shfl_xor(pp, 1);
                pp += __shfl_xor(pp, 2);
                ppv[mti][r] = pp;
            }
        }
        if ((lr & 3) == 0) {
            const int slot = ncol * 4 + (lr >> 2);
#pragma unroll
            for (int mti = 0; mti < 4; mti++) {
                const int m0 = mrow * 64 + mti * 16 + lq * 4;
                *(float4*)(part_p3 + slot * 132 + m0) =
                    make_float4(ppv[mti][0], ppv[mti][1], ppv[mti][2], ppv[mti][3]);
            }
        }
        lp0 += __shfl_xor(lp0, 16); lp0 += __shfl_xor(lp0, 32);
        lp1 += __shfl_xor(lp1, 16); lp1 += __shfl_xor(lp1, 32);
        if (lane < 16) part_l2[mrow * 128 + ncol * 32 + lane] = lp0;
        else if (lane < 32) part_l2[mrow * 128 + ncol * 32 + lane] = lp1;
        __syncthreads();

        if (t < 64) {
            const int l = t;
            float x0 = part_l2[l] + part_l2[128 + l] + bsv;
            float x1 = (l < 36) ? (part_l2[64 + l] + part_l2[192 + l] + bsv) : -3.0e38f;
            float mx = fmaxf(x0, x1);
#pragma unroll
            for (int msk = 1; msk <= 32; msk <<= 1) mx = fmaxf(mx, __shfl_xor(mx, msk));
            const float e0 = __expf(x0 - mx);
            const float e1 = (l < 36) ? __expf(x1 - mx) : 0.f;
            float sm = e0 + e1;
#pragma unroll
            for (int msk = 1; msk <= 32; msk <<= 1) sm += __shfl_xor(sm, msk);
            const float inv = 1.f / sm;
            lgp[l] = e0 * inv;
            if (l < 36) lgp[64 + l] = e1 * inv;
        } else if (t >= 128 && t < 256) {
            const int mm = t - 128;
            float s = 0.f;
#pragma unroll
            for (int sl = 0; sl < 16; sl++) s += part_p3[sl * 132 + mm];
            pool_s[mm] = s * 0.01f;
        }
        __syncthreads();

        float q2v = 0.f;
        {
            const int d = t & 63, c = t >> 6;
            float sv = 0.f;
            const int k20 = c * 7;
            const int k21 = (k20 + 7 < 50) ? (k20 + 7) : 50;
            for (int k2 = k20; k2 < k21; k2++) {
                const unsigned int vp = V_pk[k2 * 64 + d];
                const float2 lp = *(const float2*)(lgp + 2 * k2);
                sv = fmaf(lp.x, ubf16f((unsigned short)(vp & 0xffffu)), sv);
                sv = fmaf(lp.y, ubf16f((unsigned short)(vp >> 16)), sv);
            }
            part_sv[c * 64 + d] = sv;
            float ch = 0.f;
#pragma unroll
            for (int i = 0; i < 8; i++) {
                const int m2 = c * 8 + i;
                const unsigned int wp = Wc_pk[m2 * 64 + d];
                const float2 pl = *(const float2*)(pool_s + 2 * m2);
                ch = fmaf(pl.x, ubf16f((unsigned short)(wp & 0xffffu)), ch);
                ch = fmaf(pl.y, ubf16f((unsigned short)(wp >> 16)), ch);
            }
            part_ch[c * 64 + d] = ch;
            if (t < 64) q2v = q2_s[t];
        }
        __syncthreads();

        if (t < 64) {
            const int d = t;
            float sv = 0.f, ch = 0.f;
#pragma unroll
            for (int c = 0; c < 8; c++) { sv += part_sv[c * 64 + d]; ch += part_ch[c * 64 + d]; }
            ch = 1.f / (1.f + __expf(-(ch + bc_s[d])));
            const float ov = sv * q2v * ch;
            const int b = bh >> 3, hh = bh & 7;
            attn_v[(((size_t)(b * NQv + q) * NH) + hh) * 64 + d] = ov;
        } else if (qi + 1 < nq) {
            const int tq = t - 256;
            const size_t qb = ((size_t)bh * NQv + (q + 1)) * 64;
            if (tq >= 0 && tq < 64) q1_s[tq] = q1g[qb + tq];
            else if (tq >= 64 && tq < 128) q2_s[tq - 64] = q2g[qb + (tq - 64)];
        }
        __syncthreads();
    }
}

// ---------------- Kernel C: MFMA output projection ----------------
// grid (13, 8), 256 thr. out = av @ W_o + b_o, av fp32 [800][512], WT_o bf16.
__global__ __launch_bounds__(256) void out_proj_kernel(
    const float* __restrict__ x, const unsigned short* __restrict__ WT,
    const float* __restrict__ bo, float* __restrict__ out)
{
    __shared__ char A_s[64 * 144];
    __shared__ char B_s[64 * 144];

    const int t = threadIdx.x;
    const int r0 = blockIdx.x * 64;
    const int ct = blockIdx.y;

    const int lane = t & 63, wave = t >> 6;
    const int wr = wave >> 1, wc = wave & 1;
    const int lr = lane & 15, lq = lane >> 4;
    const int srow = t >> 2, sc = t & 3;

    f32x4 acc[2][2];
#pragma unroll
    for (int i = 0; i < 2; i++)
#pragma unroll
        for (int j = 0; j < 2; j++) acc[i][j] = (f32x4){0.f, 0.f, 0.f, 0.f};

    const int arow = (r0 + srow < 800) ? (r0 + srow) : 799;

    for (int kk = 0; kk < 8; kk++) {
        const int k0 = kk * 64;
#pragma unroll
        for (int uu = 0; uu < 2; uu++) {
            const int u = sc * 2 + uu;
            float4 f0 = *(const float4*)&x[(size_t)arow * 512 + k0 + u * 8];
            float4 f1 = *(const float4*)&x[(size_t)arow * 512 + k0 + u * 8 + 4];
            uint4 w;
            w.x = pkbf(f0.x, f0.y); w.y = pkbf(f0.z, f0.w);
            w.z = pkbf(f1.x, f1.y); w.w = pkbf(f1.z, f1.w);
            *(uint4*)(A_s + srow * 144 + u * 16) = w;
        }
#pragma unroll
        for (int uu = 0; uu < 2; uu++) {
            const int u = sc * 2 + uu;
            uint4 w = *(const uint4*)((const char*)(WT + (size_t)(ct * 64 + srow) * 512 + k0) + u * 16);
            *(uint4*)(B_s + srow * 144 + u * 16) = w;
        }
        __syncthreads();
#pragma unroll
        for (int ks = 0; ks < 2; ks++) {
            short8 a0 = *(const short8*)(A_s + (wr * 32 + lr) * 144 + (ks * 4 + lq) * 16);
            short8 a1 = *(const short8*)(A_s + (wr * 32 + 16 + lr) * 144 + (ks * 4 + lq) * 16);
            short8 b0 = *(const short8*)(B_s + (wc * 32 + lr) * 144 + (ks * 4 + lq) * 16);
            short8 b1 = *(const short8*)(B_s + (wc * 32 + 16 + lr) * 144 + (ks * 4 + lq) * 16);
            acc[0][0] = __builtin_amdgcn_mfma_f32_16x16x32_bf16(a0, b0, acc[0][0], 0, 0, 0);
            acc[0][1] = __builtin_amdgcn_mfma_f32_16x16x32_bf16(a0, b1, acc[0][1], 0, 0, 0);
            acc[1][0] = __builtin_amdgcn_mfma_f32_16x16x32_bf16(a1, b0, acc[1][0], 0, 0, 0);
            acc[1][1] = __builtin_amdgcn_mfma_f32_16x16x32_bf16(a1, b1, acc[1][1], 0, 0, 0);
        }
        __syncthreads();
    }

#pragma unroll
    for (int nt = 0; nt < 2; nt++) {
        const int j = ct * 64 + wc * 32 + nt * 16 + lr;
        const float bias = bo[j];
#pragma unroll
        for (int mt = 0; mt < 2; mt++) {
#pragma unroll
            for (int r = 0; r < 4; r++) {
                const int rowg = r0 + wr * 32 + mt * 16 + lq * 4 + r;
                if (rowg < 800) out[(size_t)rowg * 512 + j] = acc[mt][nt][r] + bias;
            }
        }
    }
}

extern "C" void kernel_launch(void* const* d_in, const int* in_sizes, int n_in,
                              void* d_out, int out_size, void* d_ws, size_t ws_size,
                              hipStream_t stream) {
    (void)in_sizes; (void)n_in; (void)out_size; (void)ws_size;
    const float* queries = (const float*)d_in[0];
    const float* keys    = (const float*)d_in[1];
    const float* values  = (const float*)d_in[2];
    const float* W_q1 = (const float*)d_in[3];
    const float* b_q1 = (const float*)d_in[4];
    const float* g_q1w = (const float*)d_in[5];
    const float* g_q1b = (const float*)d_in[6];
    const float* W_q2 = (const float*)d_in[7];
    const float* b_q2 = (const float*)d_in[8];
    const float* g_q2w = (const float*)d_in[9];
    const float* g_q2b = (const float*)d_in[10];
    const float* W_k = (const float*)d_in[11];
    const float* b_k = (const float*)d_in[12];
    const float* g_kw = (const float*)d_in[13];
    const float* g_kb = (const float*)d_in[14];
    const float* W_v = (const float*)d_in[15];
    const float* b_v = (const float*)d_in[16];
    const float* g_vw = (const float*)d_in[17];
    const float* g_vb = (const float*)d_in[18];
    const float* W_m = (const float*)d_in[19];
    const float* b_m = (const float*)d_in[20];
    const float* W_s = (const float*)d_in[21];
    const float* b_s = (const float*)d_in[22];
    const float* W_c = (const float*)d_in[23];
    const float* b_c = (const float*)d_in[24];
    const float* W_o = (const float*)d_in[25];
    const float* b_o = (const float*)d_in[26];

    float* ws = (float*)d_ws;
    const size_t PROJ = (size_t)BSv * NQv * 512;  // 409600 floats
    float* q1 = ws;
    float* q2 = q1 + PROJ;
    float* kk = q2 + PROJ;
    float* vv = kk + PROJ;
    float* av = vv + PROJ;   // attn_v [b][q][h][d]
    unsigned short* wt = (unsigned short*)(av + PROJ);  // 5 x [512][512] bf16

    wt_kernel<<<dim3(8, 8, 5), 256, 0, stream>>>(W_q1, W_q2, W_k, W_v, W_o, wt);

    proj_kernel<<<dim3(13, 8, 4), 256, 0, stream>>>(
        queries, keys, values, wt,
        b_q1, g_q1w, g_q1b,
        b_q2, g_q2w, g_q2b,
        b_k, g_kw, g_kb,
        b_v, g_vw, g_vb,
        q1, q2, kk, vv);

    hipFuncSetAttribute((const void*)attn_kernel,
                        hipFuncAttributeMaxDynamicSharedMemorySize, B_LDS_BYTES);
    attn_kernel<<<dim3(8, BSv * NH), 512, B_LDS_BYTES, stream>>>(
        q1, q2, kk, vv, W_m, b_m, W_s, b_s, W_c, b_c, av);

    out_proj_kernel<<<dim3(13, 8), 256, 0, stream>>>(av, wt + (size_t)4 * 512 * 512, b_o, (float*)d_out);
}